// Round 4
// baseline (2138.021 us; speedup 1.0000x reference)
//
#include <hip/hip_runtime.h>
#include <cstdint>

#define B_ 8
#define N_ 512
#define M_ 512
#define D_ 512
#define F_ 512
#define H_ 8
#define DH_ 64
#define FH_ 64

// ---- PROBE ROUND: idempotent repeat wrappers so each kernel's dispatch
// exceeds the harness fill time and appears in rocprof top-5 with counters.
// Every rep recomputes identical values (same inputs -> same output).
#define REP_K2 4
#define REP_K3 24
#define REP_K4 24

// DPP-based partial reduce (VALU pipe). bound_ctrl=true.
template <int CTRL>
__device__ __forceinline__ float dpp_add(float x) {
    int y = __builtin_amdgcn_update_dpp(0, __float_as_int(x), CTRL, 0xf, 0xf, true);
    return x + __int_as_float(y);
}

// K2 (fused K1): per (h,n): Q1 = gelu(X*diag(W1)); logits = Q1·W2^T; softmax; A.
__global__ __launch_bounds__(256, 4) void syn_k_attn(const float* __restrict__ X,
                                                     const float* __restrict__ W1,
                                                     const float* __restrict__ W2,
                                                     float* __restrict__ A) {
    int hn = blockIdx.x;
    int h = hn >> 9, n = hn & 511;
    int t = threadIdx.x;
    int wave = t >> 6, lane = t & 63;
    __shared__ float q1s[8 * 68];        // [b][d], stride 68
    __shared__ float logits[8 * 520];    // [b][m], stride 520

    #pragma unroll 1
    for (int rep = 0; rep < REP_K2; ++rep) {
        // Phase 1: Q1 for this (h,n)
        {
            int d = t & 63;
            int b0 = t >> 6;
            float w = W1[(size_t)hn * (DH_ * DH_) + d * (DH_ + 1)];
            #pragma unroll
            for (int i = 0; i < 2; ++i) {
                int bi = b0 + i * 4;
                float x = X[((size_t)(bi * N_ + n)) * D_ + h * DH_ + d];
                float v = x * w;
                q1s[bi * 68 + d] = 0.5f * v * (1.0f + erff(v * 0.70710678118654752440f));
            }
        }
        __syncthreads();

        int mr = lane >> 3, c = lane & 7;
        float4 qa[8], qb[8];
        #pragma unroll
        for (int b = 0; b < 8; ++b) {
            qa[b] = *(const float4*)&q1s[b * 68 + c * 8];
            qb[b] = *(const float4*)&q1s[b * 68 + c * 8 + 4];
        }

        const float* w2 = W2 + (size_t)hn * ((size_t)M_ * DH_);
        #pragma unroll 2
        for (int g = 0; g < 16; ++g) {
            int m = (wave + g * 4) * 8 + mr;
            const float* wr = w2 + (size_t)m * DH_ + c * 8;
            float4 wa = *(const float4*)wr;
            float4 wb = *(const float4*)(wr + 4);
            float acc[8];
            #pragma unroll
            for (int b = 0; b < 8; ++b) {
                float a0 = wa.x * qa[b].x + wa.y * qa[b].y + wa.z * qa[b].z + wa.w * qa[b].w
                         + wb.x * qb[b].x + wb.y * qb[b].y + wb.z * qb[b].z + wb.w * qb[b].w;
                a0 = dpp_add<0xB1>(a0);
                a0 = dpp_add<0x4E>(a0);
                a0 = dpp_add<0x124>(a0);
                acc[b] = a0;
            }
            float lo = c == 0 ? acc[0] : c == 1 ? acc[1] : c == 2 ? acc[2] : acc[3];
            float hi = c == 0 ? acc[4] : c == 1 ? acc[5] : c == 2 ? acc[6] : acc[7];
            if (c < 4) {
                logits[c * 520 + m] = lo;
                logits[(c + 4) * 520 + m] = hi;
            }
        }
        __syncthreads();

        // Phase 3: softmax over m
        for (int bb = wave; bb < 8; bb += 4) {
            const float* lrow = &logits[bb * 520 + lane * 8];
            float4 va = *(const float4*)lrow;
            float4 vb = *(const float4*)(lrow + 4);
            float v[8] = {va.x, va.y, va.z, va.w, vb.x, vb.y, vb.z, vb.w};
            float mx = v[0];
            #pragma unroll
            for (int i = 1; i < 8; ++i) mx = fmaxf(mx, v[i]);
            #pragma unroll
            for (int s = 1; s < 64; s <<= 1) mx = fmaxf(mx, __shfl_xor(mx, s));
            float e[8]; float sum = 0.f;
            #pragma unroll
            for (int i = 0; i < 8; ++i) { e[i] = expf(v[i] - mx); sum += e[i]; }
            #pragma unroll
            for (int s = 1; s < 64; s <<= 1) sum += __shfl_xor(sum, s);
            float inv = 1.0f / sum;
            float* outp = A + ((size_t)(bb * H_ + h) * N_ + n) * M_ + lane * 8;
            float4 o0 = make_float4(e[0] * inv, e[1] * inv, e[2] * inv, e[3] * inv);
            float4 o1 = make_float4(e[4] * inv, e[5] * inv, e[6] * inv, e[7] * inv);
            *(float4*)outp = o0;
            *(float4*)(outp + 4) = o1;
        }
        __syncthreads();
    }
}

// K3: per (b,h): Y[n,f] = (A[n,:]·Vh[:,f]) * WVdiag[f]. 64x64 tile, 4x4/thread.
__global__ __launch_bounds__(256) void syn_k_pv(const float* __restrict__ A,
                                                const float* __restrict__ V,
                                                const float* __restrict__ WV,
                                                float* __restrict__ Y) {
    int bh = blockIdx.y;
    int b = bh >> 3, h = bh & 7;
    int n0 = blockIdx.x * 64;
    int t = threadIdx.x;
    int tx = t & 15, ty = t >> 4;
    __shared__ float Alds[64 * 68];
    __shared__ float Vlds[64 * 68];
    const float* Abase = A + ((size_t)bh * N_ + n0) * M_;
    const float* Vbase = V + (size_t)b * ((size_t)M_ * F_) + h * FH_;

    #pragma unroll 1
    for (int rep = 0; rep < REP_K3; ++rep) {
        float acc[4][4] = {};
        for (int m0 = 0; m0 < M_; m0 += 64) {
            #pragma unroll
            for (int it = 0; it < 4; ++it) {
                int e = t * 4 + it * 1024;
                int r = e >> 6, k = e & 63;
                float4 a4 = *(const float4*)(Abase + (size_t)r * M_ + m0 + k);
                Alds[(k + 0) * 68 + r] = a4.x;
                Alds[(k + 1) * 68 + r] = a4.y;
                Alds[(k + 2) * 68 + r] = a4.z;
                Alds[(k + 3) * 68 + r] = a4.w;
                float4 v4 = *(const float4*)(Vbase + (size_t)(m0 + r) * F_ + k);
                *(float4*)&Vlds[r * 68 + k] = v4;
            }
            __syncthreads();
            #pragma unroll 4
            for (int k = 0; k < 64; ++k) {
                float4 a4 = *(const float4*)&Alds[k * 68 + ty * 4];
                float4 v4 = *(const float4*)&Vlds[k * 68 + tx * 4];
                float ar[4] = {a4.x, a4.y, a4.z, a4.w};
                float vr[4] = {v4.x, v4.y, v4.z, v4.w};
                #pragma unroll
                for (int i = 0; i < 4; ++i)
                    #pragma unroll
                    for (int j = 0; j < 4; ++j)
                        acc[i][j] += ar[i] * vr[j];
            }
            __syncthreads();
        }
        float s[4];
        #pragma unroll
        for (int j = 0; j < 4; ++j)
            s[j] = WV[(size_t)h * (FH_ * FH_) + (tx * 4 + j) * (FH_ + 1)];
        #pragma unroll
        for (int i = 0; i < 4; ++i) {
            int row = n0 + ty * 4 + i;
            float4 o = make_float4(acc[i][0] * s[0], acc[i][1] * s[1],
                                   acc[i][2] * s[2], acc[i][3] * s[3]);
            *(float4*)(Y + ((size_t)(b * N_ + row)) * F_ + h * FH_ + tx * 4) = o;
        }
    }
}

// K4: out[r,f'] = Y[r,:]·Ow[f',:] + Ob[f'].  64x64 tile, 4x4/thread.
__global__ __launch_bounds__(256) void syn_k_out(const float* __restrict__ Yg,
                                                 const float* __restrict__ Ow,
                                                 const float* __restrict__ Ob,
                                                 float* __restrict__ out) {
    int r0 = blockIdx.y * 64;
    int f0 = blockIdx.x * 64;
    int t = threadIdx.x;
    int tx = t & 15, ty = t >> 4;
    __shared__ float Ylds[64 * 68];
    __shared__ float Wlds[64 * 68];

    #pragma unroll 1
    for (int rep = 0; rep < REP_K4; ++rep) {
        float acc[4][4] = {};
        for (int k0 = 0; k0 < F_; k0 += 64) {
            #pragma unroll
            for (int it = 0; it < 4; ++it) {
                int e = t * 4 + it * 1024;
                int r = e >> 6, k = e & 63;
                float4 y4 = *(const float4*)(Yg + (size_t)(r0 + r) * F_ + k0 + k);
                Ylds[(k + 0) * 68 + r] = y4.x;
                Ylds[(k + 1) * 68 + r] = y4.y;
                Ylds[(k + 2) * 68 + r] = y4.z;
                Ylds[(k + 3) * 68 + r] = y4.w;
                float4 w4 = *(const float4*)(Ow + (size_t)(f0 + r) * F_ + k0 + k);
                Wlds[(k + 0) * 68 + r] = w4.x;
                Wlds[(k + 1) * 68 + r] = w4.y;
                Wlds[(k + 2) * 68 + r] = w4.z;
                Wlds[(k + 3) * 68 + r] = w4.w;
            }
            __syncthreads();
            #pragma unroll 4
            for (int k = 0; k < 64; ++k) {
                float4 y4 = *(const float4*)&Ylds[k * 68 + ty * 4];
                float4 w4 = *(const float4*)&Wlds[k * 68 + tx * 4];
                float yr[4] = {y4.x, y4.y, y4.z, y4.w};
                float wr[4] = {w4.x, w4.y, w4.z, w4.w};
                #pragma unroll
                for (int i = 0; i < 4; ++i)
                    #pragma unroll
                    for (int j = 0; j < 4; ++j)
                        acc[i][j] += yr[i] * wr[j];
            }
            __syncthreads();
        }
        float bb[4];
        #pragma unroll
        for (int j = 0; j < 4; ++j) bb[j] = Ob[f0 + tx * 4 + j];
        #pragma unroll
        for (int i = 0; i < 4; ++i) {
            int row = r0 + ty * 4 + i;
            float4 o = make_float4(acc[i][0] + bb[0], acc[i][1] + bb[1],
                                   acc[i][2] + bb[2], acc[i][3] + bb[3]);
            *(float4*)(out + (size_t)row * F_ + f0 + tx * 4) = o;
        }
    }
}

extern "C" void kernel_launch(void* const* d_in, const int* in_sizes, int n_in,
                              void* d_out, int out_size, void* d_ws, size_t ws_size,
                              hipStream_t stream) {
    const float* X  = (const float*)d_in[0];
    const float* V  = (const float*)d_in[1];
    const float* W1 = (const float*)d_in[2];
    const float* W2 = (const float*)d_in[3];
    const float* WV = (const float*)d_in[4];
    const float* Ow = (const float*)d_in[5];
    const float* Ob = (const float*)d_in[6];
    float* out = (float*)d_out;

    float* ws = (float*)d_ws;
    float* A  = ws;                                   // B*H*N*M = 16.78M floats
    float* Y  = A + (size_t)B_ * H_ * N_ * M_;        // B*N*F   = 2.1M floats

    syn_k_attn<<<H_ * N_, 256, 0, stream>>>(X, W1, W2, A);
    syn_k_pv<<<dim3(N_ / 64, B_ * H_), 256, 0, stream>>>(A, V, WV, Y);
    syn_k_out<<<dim3(F_ / 64, (B_ * N_) / 64), 256, 0, stream>>>(Y, Ow, Ob, out);
}

// Round 5
// 207.080 us; speedup vs baseline: 10.3246x; 10.3246x over previous
//
#include <hip/hip_runtime.h>
#include <cstdint>

#define B_ 8
#define N_ 512
#define M_ 512
#define D_ 512
#define F_ 512
#define H_ 8
#define DH_ 64
#define FH_ 64

// DPP-based partial reduce (VALU pipe). bound_ctrl=true.
template <int CTRL>
__device__ __forceinline__ float dpp_add(float x) {
    int y = __builtin_amdgcn_update_dpp(0, __float_as_int(x), CTRL, 0xf, 0xf, true);
    return x + __int_as_float(y);
}

// K2 (fused K1): per (h,n): Q1 = gelu(X*diag(W1)); logits = Q1·W2^T; softmax; A.
__global__ __launch_bounds__(256, 4) void syn_k_attn(const float* __restrict__ X,
                                                     const float* __restrict__ W1,
                                                     const float* __restrict__ W2,
                                                     float* __restrict__ A) {
    int hn = blockIdx.x;
    int h = hn >> 9, n = hn & 511;
    int t = threadIdx.x;
    int wave = t >> 6, lane = t & 63;
    __shared__ float q1s[8 * 68];        // [b][d], stride 68
    __shared__ float logits[8 * 520];    // [b][m], stride 520

    // Phase 1: Q1 for this (h,n)
    {
        int d = t & 63;
        int b0 = t >> 6;
        float w = W1[(size_t)hn * (DH_ * DH_) + d * (DH_ + 1)];
        #pragma unroll
        for (int i = 0; i < 2; ++i) {
            int bi = b0 + i * 4;
            float x = X[((size_t)(bi * N_ + n)) * D_ + h * DH_ + d];
            float v = x * w;
            q1s[bi * 68 + d] = 0.5f * v * (1.0f + erff(v * 0.70710678118654752440f));
        }
    }
    __syncthreads();

    int mr = lane >> 3, c = lane & 7;
    float4 qa[8], qb[8];
    #pragma unroll
    for (int b = 0; b < 8; ++b) {
        qa[b] = *(const float4*)&q1s[b * 68 + c * 8];
        qb[b] = *(const float4*)&q1s[b * 68 + c * 8 + 4];
    }

    const float* w2 = W2 + (size_t)hn * ((size_t)M_ * DH_);
    #pragma unroll 4
    for (int g = 0; g < 16; ++g) {
        int m = (wave + g * 4) * 8 + mr;
        const float* wr = w2 + (size_t)m * DH_ + c * 8;
        float4 wa = *(const float4*)wr;
        float4 wb = *(const float4*)(wr + 4);
        float acc[8];
        #pragma unroll
        for (int b = 0; b < 8; ++b) {
            float a0 = wa.x * qa[b].x + wa.y * qa[b].y + wa.z * qa[b].z + wa.w * qa[b].w
                     + wb.x * qb[b].x + wb.y * qb[b].y + wb.z * qb[b].z + wb.w * qb[b].w;
            a0 = dpp_add<0xB1>(a0);    // + lane^1 (quad_perm)
            a0 = dpp_add<0x4E>(a0);    // + lane^2 (quad_perm)
            a0 = dpp_add<0x124>(a0);   // row_ror:4 — valid on (lane%16)<4 i.e. c<4
            acc[b] = a0;
        }
        float lo = c == 0 ? acc[0] : c == 1 ? acc[1] : c == 2 ? acc[2] : acc[3];
        float hi = c == 0 ? acc[4] : c == 1 ? acc[5] : c == 2 ? acc[6] : acc[7];
        if (c < 4) {
            logits[c * 520 + m] = lo;
            logits[(c + 4) * 520 + m] = hi;
        }
    }
    __syncthreads();

    // Phase 3: softmax over m; wave handles rows b = wave, wave+4
    for (int bb = wave; bb < 8; bb += 4) {
        const float* lrow = &logits[bb * 520 + lane * 8];
        float4 va = *(const float4*)lrow;
        float4 vb = *(const float4*)(lrow + 4);
        float v[8] = {va.x, va.y, va.z, va.w, vb.x, vb.y, vb.z, vb.w};
        float mx = v[0];
        #pragma unroll
        for (int i = 1; i < 8; ++i) mx = fmaxf(mx, v[i]);
        #pragma unroll
        for (int s = 1; s < 64; s <<= 1) mx = fmaxf(mx, __shfl_xor(mx, s));
        float e[8]; float sum = 0.f;
        #pragma unroll
        for (int i = 0; i < 8; ++i) { e[i] = expf(v[i] - mx); sum += e[i]; }
        #pragma unroll
        for (int s = 1; s < 64; s <<= 1) sum += __shfl_xor(sum, s);
        float inv = 1.0f / sum;
        float* outp = A + ((size_t)(bb * H_ + h) * N_ + n) * M_ + lane * 8;
        float4 o0 = make_float4(e[0] * inv, e[1] * inv, e[2] * inv, e[3] * inv);
        float4 o1 = make_float4(e[4] * inv, e[5] * inv, e[6] * inv, e[7] * inv);
        *(float4*)outp = o0;
        *(float4*)(outp + 4) = o1;
    }
}

// Swizzled transposed tile: addr(k, r) = k*64 + 4*(((r>>2) ^ (k>>2)) & 15) + (r&3).
// Writes: 2-way bank alias (free). b128 reads: 16B-aligned, conflict-free.

// K3: per (b,h): Y[n,f] = (A[n,:]·Vh[:,f]) * WVdiag[f]. 64x64 tile, 4x4/thread.
__global__ __launch_bounds__(256) void syn_k_pv(const float* __restrict__ A,
                                                const float* __restrict__ V,
                                                const float* __restrict__ WV,
                                                float* __restrict__ Y) {
    int bh = blockIdx.y;
    int b = bh >> 3, h = bh & 7;
    int n0 = blockIdx.x * 64;
    int t = threadIdx.x;
    int tx = t & 15, ty = t >> 4;
    __shared__ float Alds[64 * 64];   // swizzled [m][n]
    __shared__ float Vlds[64 * 64];   // natural  [m][f]
    float acc[4][4] = {};
    const float* Abase = A + ((size_t)bh * N_ + n0) * M_;
    const float* Vbase = V + (size_t)b * ((size_t)M_ * F_) + h * FH_;
    int kk = tx * 4;
    for (int m0 = 0; m0 < M_; m0 += 64) {
        #pragma unroll
        for (int it = 0; it < 4; ++it) {
            int r = ty + it * 16;
            float4 a4 = *(const float4*)(Abase + (size_t)r * M_ + m0 + kk);
            int slot = ((r >> 2) ^ tx) & 15;
            float* p = &Alds[kk * 64 + slot * 4 + (r & 3)];
            p[0] = a4.x; p[64] = a4.y; p[128] = a4.z; p[192] = a4.w;
            float4 v4 = *(const float4*)(Vbase + (size_t)(m0 + r) * F_ + kk);
            *(float4*)&Vlds[r * 64 + kk] = v4;
        }
        __syncthreads();
        #pragma unroll 2
        for (int k4 = 0; k4 < 16; ++k4) {
            int sa = ((ty ^ k4) & 15) * 4;
            #pragma unroll
            for (int kj = 0; kj < 4; ++kj) {
                int k = k4 * 4 + kj;
                float4 a4 = *(const float4*)&Alds[k * 64 + sa];
                float4 v4 = *(const float4*)&Vlds[k * 64 + tx * 4];
                float ar[4] = {a4.x, a4.y, a4.z, a4.w};
                float vr[4] = {v4.x, v4.y, v4.z, v4.w};
                #pragma unroll
                for (int i = 0; i < 4; ++i)
                    #pragma unroll
                    for (int j = 0; j < 4; ++j)
                        acc[i][j] += ar[i] * vr[j];
            }
        }
        __syncthreads();
    }
    float s[4];
    #pragma unroll
    for (int j = 0; j < 4; ++j)
        s[j] = WV[(size_t)h * (FH_ * FH_) + (tx * 4 + j) * (FH_ + 1)];
    #pragma unroll
    for (int i = 0; i < 4; ++i) {
        int row = n0 + ty * 4 + i;
        float4 o = make_float4(acc[i][0] * s[0], acc[i][1] * s[1],
                               acc[i][2] * s[2], acc[i][3] * s[3]);
        *(float4*)(Y + ((size_t)(b * N_ + row)) * F_ + h * FH_ + tx * 4) = o;
    }
}

// K4: out[r,f'] = Y[r,:]·Ow[f',:] + Ob[f'].  64x64 tile, 4x4/thread.
__global__ __launch_bounds__(256) void syn_k_out(const float* __restrict__ Yg,
                                                 const float* __restrict__ Ow,
                                                 const float* __restrict__ Ob,
                                                 float* __restrict__ out) {
    int r0 = blockIdx.y * 64;
    int f0 = blockIdx.x * 64;
    int t = threadIdx.x;
    int tx = t & 15, ty = t >> 4;
    __shared__ float Ylds[64 * 64];   // swizzled [k][r]
    __shared__ float Wlds[64 * 64];   // swizzled [k][f']
    float acc[4][4] = {};
    int kk = tx * 4;
    for (int k0 = 0; k0 < F_; k0 += 64) {
        #pragma unroll
        for (int it = 0; it < 4; ++it) {
            int r = ty + it * 16;
            int slot = ((r >> 2) ^ tx) & 15;
            float4 y4 = *(const float4*)(Yg + (size_t)(r0 + r) * F_ + k0 + kk);
            float* py = &Ylds[kk * 64 + slot * 4 + (r & 3)];
            py[0] = y4.x; py[64] = y4.y; py[128] = y4.z; py[192] = y4.w;
            float4 w4 = *(const float4*)(Ow + (size_t)(f0 + r) * F_ + k0 + kk);
            float* pw = &Wlds[kk * 64 + slot * 4 + (r & 3)];
            pw[0] = w4.x; pw[64] = w4.y; pw[128] = w4.z; pw[192] = w4.w;
        }
        __syncthreads();
        #pragma unroll 2
        for (int k4 = 0; k4 < 16; ++k4) {
            int sy = ((ty ^ k4) & 15) * 4;
            int sw = ((tx ^ k4) & 15) * 4;
            #pragma unroll
            for (int kj = 0; kj < 4; ++kj) {
                int k = k4 * 4 + kj;
                float4 y4 = *(const float4*)&Ylds[k * 64 + sy];
                float4 w4 = *(const float4*)&Wlds[k * 64 + sw];
                float yr[4] = {y4.x, y4.y, y4.z, y4.w};
                float wr[4] = {w4.x, w4.y, w4.z, w4.w};
                #pragma unroll
                for (int i = 0; i < 4; ++i)
                    #pragma unroll
                    for (int j = 0; j < 4; ++j)
                        acc[i][j] += yr[i] * wr[j];
            }
        }
        __syncthreads();
    }
    float bb[4];
    #pragma unroll
    for (int j = 0; j < 4; ++j) bb[j] = Ob[f0 + tx * 4 + j];
    #pragma unroll
    for (int i = 0; i < 4; ++i) {
        int row = r0 + ty * 4 + i;
        float4 o = make_float4(acc[i][0] + bb[0], acc[i][1] + bb[1],
                               acc[i][2] + bb[2], acc[i][3] + bb[3]);
        *(float4*)(out + (size_t)row * F_ + f0 + tx * 4) = o;
    }
}

extern "C" void kernel_launch(void* const* d_in, const int* in_sizes, int n_in,
                              void* d_out, int out_size, void* d_ws, size_t ws_size,
                              hipStream_t stream) {
    const float* X  = (const float*)d_in[0];
    const float* V  = (const float*)d_in[1];
    const float* W1 = (const float*)d_in[2];
    const float* W2 = (const float*)d_in[3];
    const float* WV = (const float*)d_in[4];
    const float* Ow = (const float*)d_in[5];
    const float* Ob = (const float*)d_in[6];
    float* out = (float*)d_out;

    float* ws = (float*)d_ws;
    float* A  = ws;                                   // B*H*N*M = 16.78M floats
    float* Y  = A + (size_t)B_ * H_ * N_ * M_;        // B*N*F   = 2.1M floats

    syn_k_attn<<<H_ * N_, 256, 0, stream>>>(X, W1, W2, A);
    syn_k_pv<<<dim3(N_ / 64, B_ * H_), 256, 0, stream>>>(A, V, WV, Y);
    syn_k_out<<<dim3(F_ / 64, (B_ * N_) / 64), 256, 0, stream>>>(Y, Ow, Ob, out);
}